// Round 2
// baseline (1683.948 us; speedup 1.0000x reference)
//
#include <hip/hip_runtime.h>
#include <cstdint>
#include <cstddef>

// ---------------------------------------------------------------------------
// NoiseBlockMoE (B=4,T=1024,D=1024,H=16,E=8,top2,FF=4096)
// Round 2: fp32-accurate pre-router path (split-bf16 MFMA GEMMs + fp32 flash
// attention) to eliminate router top-2 flips; bf16 MFMA experts post-router.
// ---------------------------------------------------------------------------

#define AS1 __attribute__((address_space(1)))
#define AS3 __attribute__((address_space(3)))

typedef unsigned short u16;
typedef __attribute__((ext_vector_type(8))) short short8;   // 8 bf16 = 4 VGPR
typedef __attribute__((ext_vector_type(4))) float f32x4;

constexpr int Bc = 4, Tc = 1024, Dc = 1024, Hc = 16, Ec = 8, FFc = 4096;
constexpr int Mtok = Bc * Tc;   // 4096 tokens

// plane strides (elements)
constexpr size_t PS_WQKV = (size_t)3 * Dc * Dc;   // 3145728
constexpr size_t PS_WPROJ = (size_t)Dc * Dc;      // 1048576
constexpr size_t PS_H = (size_t)Mtok * Dc;        // 4194304

__device__ __forceinline__ u16 f2bf(float f) {              // RNE f32->bf16
  unsigned u = __float_as_uint(f);
  u += 0x7fffu + ((u >> 16) & 1u);
  return (u16)(u >> 16);
}
__device__ __forceinline__ float bf2f(u16 v) { return __uint_as_float(((unsigned)v) << 16); }
__device__ __forceinline__ float gelu_f(float v) {          // exact GELU (erf)
  return 0.5f * v * (1.0f + erff(v * 0.70710678118654752440f));
}

// ---------------------------------------------------------------- cvt f32->bf16 (plain)
__global__ __launch_bounds__(256) void cvt_bf16_kernel(const float* __restrict__ in,
                                                       u16* __restrict__ out, int n4) {
  int i = blockIdx.x * 256 + threadIdx.x;
  if (i >= n4) return;
  float4 v = reinterpret_cast<const float4*>(in)[i];
  uint2 o;
  o.x = (unsigned)f2bf(v.x) | ((unsigned)f2bf(v.y) << 16);
  o.y = (unsigned)f2bf(v.z) | ((unsigned)f2bf(v.w) << 16);
  reinterpret_cast<uint2*>(out)[i] = o;
}

// ---------------------------------------------------------------- fp32 -> 3 bf16 planes
__global__ __launch_bounds__(256) void split3_kernel(const float* __restrict__ in,
                                                     u16* __restrict__ out,
                                                     size_t ps, int n4) {
  int i = blockIdx.x * 256 + threadIdx.x;
  if (i >= n4) return;
  float4 v = reinterpret_cast<const float4*>(in)[i];
  float a[4] = {v.x, v.y, v.z, v.w};
  unsigned h[4], md[4], lo[4];
#pragma unroll
  for (int j = 0; j < 4; ++j) {
    u16 hh = f2bf(a[j]); float r = a[j] - bf2f(hh);
    u16 mm = f2bf(r);    float r2 = r - bf2f(mm);
    u16 ll = f2bf(r2);
    h[j] = hh; md[j] = mm; lo[j] = ll;
  }
  uint2 o0, o1, o2;
  o0.x = h[0] | (h[1] << 16);  o0.y = h[2] | (h[3] << 16);
  o1.x = md[0] | (md[1] << 16); o1.y = md[2] | (md[3] << 16);
  o2.x = lo[0] | (lo[1] << 16); o2.y = lo[2] | (lo[3] << 16);
  const size_t base = (size_t)i * 4;
  *(uint2*)&out[base] = o0;
  *(uint2*)&out[ps + base] = o1;
  *(uint2*)&out[2 * ps + base] = o2;
}

// ---------------------------------------------------------------- LN1 (+c) -> 3 bf16 planes
__global__ __launch_bounds__(256) void ln1_kernel(const float* __restrict__ x,
                                                  const float* __restrict__ w,
                                                  const float* __restrict__ c,
                                                  u16* __restrict__ hp) {
  const int row = blockIdx.x, tid = threadIdx.x;
  const int b = row >> 10;   // T=1024
  const float4 v = reinterpret_cast<const float4*>(x + (size_t)row * Dc)[tid];
  __shared__ float red[256];
  red[tid] = v.x + v.y + v.z + v.w;
  __syncthreads();
  for (int s = 128; s > 0; s >>= 1) { if (tid < s) red[tid] += red[tid + s]; __syncthreads(); }
  const float mu = red[0] * (1.0f / Dc);
  __syncthreads();
  const float dx = v.x - mu, dy = v.y - mu, dz = v.z - mu, dw = v.w - mu;
  red[tid] = dx * dx + dy * dy + dz * dz + dw * dw;
  __syncthreads();
  for (int s = 128; s > 0; s >>= 1) { if (tid < s) red[tid] += red[tid + s]; __syncthreads(); }
  const float rs = rsqrtf(red[0] * (1.0f / Dc) + 1e-5f);
  const float4 wv = reinterpret_cast<const float4*>(w)[tid];
  const float4 cv = reinterpret_cast<const float4*>(c + (size_t)b * Dc)[tid];
  float a[4];
  a[0] = dx * rs * wv.x + cv.x; a[1] = dy * rs * wv.y + cv.y;
  a[2] = dz * rs * wv.z + cv.z; a[3] = dw * rs * wv.w + cv.w;
  unsigned h[4], md[4], lo[4];
#pragma unroll
  for (int j = 0; j < 4; ++j) {
    u16 hh = f2bf(a[j]); float r = a[j] - bf2f(hh);
    u16 mm = f2bf(r);    float r2 = r - bf2f(mm);
    u16 ll = f2bf(r2);
    h[j] = hh; md[j] = mm; lo[j] = ll;
  }
  uint2 o0, o1, o2;
  o0.x = h[0] | (h[1] << 16);  o0.y = h[2] | (h[3] << 16);
  o1.x = md[0] | (md[1] << 16); o1.y = md[2] | (md[3] << 16);
  o2.x = lo[0] | (lo[1] << 16); o2.y = lo[2] | (lo[3] << 16);
  const size_t base = (size_t)row * Dc + tid * 4;
  *(uint2*)&hp[base] = o0;
  *(uint2*)&hp[PS_H + base] = o1;
  *(uint2*)&hp[2 * PS_H + base] = o2;
}

// ---------------------------------------------------------------- LN2 -> f32 (d_out) + bf16
__global__ __launch_bounds__(256) void ln2_kernel(const float* __restrict__ xin,
                                                  const float* __restrict__ w,
                                                  float* __restrict__ xf,
                                                  u16* __restrict__ xb) {
  const int row = blockIdx.x, tid = threadIdx.x;
  const float4 v = reinterpret_cast<const float4*>(xin + (size_t)row * Dc)[tid];
  __shared__ float red[256];
  red[tid] = v.x + v.y + v.z + v.w;
  __syncthreads();
  for (int s = 128; s > 0; s >>= 1) { if (tid < s) red[tid] += red[tid + s]; __syncthreads(); }
  const float mu = red[0] * (1.0f / Dc);
  __syncthreads();
  const float dx = v.x - mu, dy = v.y - mu, dz = v.z - mu, dw = v.w - mu;
  red[tid] = dx * dx + dy * dy + dz * dz + dw * dw;
  __syncthreads();
  for (int s = 128; s > 0; s >>= 1) { if (tid < s) red[tid] += red[tid + s]; __syncthreads(); }
  const float rs = rsqrtf(red[0] * (1.0f / Dc) + 1e-5f);
  const float4 wv = reinterpret_cast<const float4*>(w)[tid];
  float4 ov;
  ov.x = dx * rs * wv.x; ov.y = dy * rs * wv.y; ov.z = dz * rs * wv.z; ov.w = dw * rs * wv.w;
  reinterpret_cast<float4*>(xf + (size_t)row * Dc)[tid] = ov;
  uint2 o;
  o.x = (unsigned)f2bf(ov.x) | ((unsigned)f2bf(ov.y) << 16);
  o.y = (unsigned)f2bf(ov.z) | ((unsigned)f2bf(ov.w) << 16);
  reinterpret_cast<uint2*>(xb + (size_t)row * Dc)[tid] = o;
}

// ---------------------------------------------------------------- MFMA GEMM core (single, bf16)
__device__ __forceinline__ void gemm_mfma_core(const u16* a0, const u16* a1,
                                               const u16* b0, const u16* b1,
                                               int K, u16* As, u16* Bs, f32x4 acc[4][4]) {
  const int tid = threadIdx.x;
  const int lane = tid & 63;
  const int wave = tid >> 6;
  const int wm = (wave & 1) * 64;
  const int wn = (wave >> 1) * 64;
  const int frow = lane & 15;
  const int fk = (lane >> 4) * 8;
  int aoff[4], boff[4];
#pragma unroll
  for (int t = 0; t < 4; ++t) {
    aoff[t] = (wm + t * 16 + frow) * 32 + fk;
    boff[t] = (wn + t * 16 + frow) * 32 + fk;
  }
  const int lds0 = tid * 8;
  for (int k0 = 0; k0 < K; k0 += 32) {
    __builtin_amdgcn_global_load_lds((AS1 void*)a0, (AS3 void*)(As + lds0), 16, 0, 0);
    __builtin_amdgcn_global_load_lds((AS1 void*)a1, (AS3 void*)(As + 2048 + lds0), 16, 0, 0);
    __builtin_amdgcn_global_load_lds((AS1 void*)b0, (AS3 void*)(Bs + lds0), 16, 0, 0);
    __builtin_amdgcn_global_load_lds((AS1 void*)b1, (AS3 void*)(Bs + 2048 + lds0), 16, 0, 0);
    a0 += 32; a1 += 32; b0 += 32; b1 += 32;
    __syncthreads();
    short8 af[4], bfr[4];
#pragma unroll
    for (int t = 0; t < 4; ++t) af[t] = *(const short8*)(As + aoff[t]);
#pragma unroll
    for (int t = 0; t < 4; ++t) bfr[t] = *(const short8*)(Bs + boff[t]);
#pragma unroll
    for (int mt = 0; mt < 4; ++mt)
#pragma unroll
      for (int nt = 0; nt < 4; ++nt)
        acc[mt][nt] = __builtin_amdgcn_mfma_f32_16x16x32_bf16(af[mt], bfr[nt], acc[mt][nt], 0, 0, 0);
    __syncthreads();
  }
}

// ---------------------------------------------------------------- split-3 GEMM core: 6 plane-pair sweeps
// Terms hh, hm, mh, mm, hl, lh capture fp32 precision (dropped <= 2^-27 rel).
__device__ __forceinline__ void gemm_split_core(const u16* A0, const u16* A1, size_t Aps,
                                                const u16* B0, const u16* B1, size_t Bps,
                                                int K, u16* As, u16* Bs, f32x4 acc[4][4]) {
  const int PA[6] = {0, 0, 1, 1, 0, 2};
  const int PB[6] = {0, 1, 0, 1, 2, 0};
  for (int t6 = 0; t6 < 6; ++t6) {
    gemm_mfma_core(A0 + PA[t6] * Aps, A1 + PA[t6] * Aps,
                   B0 + PB[t6] * Bps, B1 + PB[t6] * Bps, K, As, Bs, acc);
  }
}

// ---------------------------------------------------------------- qkv split GEMM -> fp32
__global__ __launch_bounds__(256) void gemm_qkv_kernel(const u16* __restrict__ A,
                                                       const u16* __restrict__ Bw,
                                                       float* __restrict__ Cout) {
  __shared__ u16 As[128 * 32], Bs[128 * 32];
  const int bn = blockIdx.x, bm = blockIdx.y, tid = threadIdx.x;
  const int r = tid >> 2, kk = (tid & 3) * 8;
  const u16* a0 = A + (size_t)(bm * 128 + r) * 1024 + kk;
  const u16* a1 = a0 + (size_t)64 * 1024;
  const u16* b0 = Bw + (size_t)(bn * 128 + r) * 1024 + kk;
  const u16* b1 = b0 + (size_t)64 * 1024;
  f32x4 acc[4][4] = {};
  gemm_split_core(a0, a1, PS_H, b0, b1, PS_WQKV, 1024, As, Bs, acc);
  const int lane = tid & 63, wave = tid >> 6;
  const int wm = (wave & 1) * 64, wn = (wave >> 1) * 64;
  const int col = lane & 15, rb = (lane >> 4) * 4;
#pragma unroll
  for (int mt = 0; mt < 4; ++mt)
#pragma unroll
    for (int rr = 0; rr < 4; ++rr) {
      const int m = bm * 128 + wm + mt * 16 + rb + rr;
#pragma unroll
      for (int nt = 0; nt < 4; ++nt) {
        const int n = bn * 128 + wn + nt * 16 + col;
        Cout[(size_t)m * 3072 + n] = acc[mt][nt][rr];
      }
    }
}

// ---------------------------------------------------------------- proj split GEMM + residual -> fp32
__global__ __launch_bounds__(256) void gemm_proj_kernel(const u16* __restrict__ A,
                                                        const u16* __restrict__ Bw,
                                                        const float* __restrict__ xres,
                                                        float* __restrict__ xmid) {
  __shared__ u16 As[128 * 32], Bs[128 * 32];
  const int bn = blockIdx.x, bm = blockIdx.y, tid = threadIdx.x;
  const int r = tid >> 2, kk = (tid & 3) * 8;
  const u16* a0 = A + (size_t)(bm * 128 + r) * 1024 + kk;
  const u16* a1 = a0 + (size_t)64 * 1024;
  const u16* b0 = Bw + (size_t)(bn * 128 + r) * 1024 + kk;
  const u16* b1 = b0 + (size_t)64 * 1024;
  f32x4 acc[4][4] = {};
  gemm_split_core(a0, a1, PS_H, b0, b1, PS_WPROJ, 1024, As, Bs, acc);
  const int lane = tid & 63, wave = tid >> 6;
  const int wm = (wave & 1) * 64, wn = (wave >> 1) * 64;
  const int col = lane & 15, rb = (lane >> 4) * 4;
#pragma unroll
  for (int mt = 0; mt < 4; ++mt)
#pragma unroll
    for (int rr = 0; rr < 4; ++rr) {
      const int m = bm * 128 + wm + mt * 16 + rb + rr;
#pragma unroll
      for (int nt = 0; nt < 4; ++nt) {
        const int n = bn * 128 + wn + nt * 16 + col;
        xmid[(size_t)m * 1024 + n] = xres[(size_t)m * 1024 + n] + acc[mt][nt][rr];
      }
    }
}

// ---------------------------------------------------------------- attention, fp32 flash (scalar)
// Block = 4 waves = 4 consecutive q rows of one (b,h). K rows + V^T in LDS.
__global__ __launch_bounds__(256) void attn_f32_kernel(const float* __restrict__ qkv,
                                                       float* __restrict__ obuf) {
  const int tid = threadIdx.x, lane = tid & 63, w = tid >> 6;
  const int bh = blockIdx.y, b = bh >> 4, h = bh & 15;
  const int q0 = blockIdx.x * 4, qi = q0 + w;
  __shared__ float Ks[64 * 68];          // K rows, stride 68
  __shared__ float Vt[64 * 68];          // V transposed: Vt[d][k], stride 68
  __shared__ float qs[4][64];
  __shared__ float ps[4][64];
  qs[w][lane] = qkv[((size_t)(b * Tc + qi)) * 3072 + h * 64 + lane] * 0.125f;  // 1/sqrt(64), exact
  const float* kb = qkv + (size_t)b * Tc * 3072 + 1024 + h * 64;
  const float* vb = kb + 1024;
  float m = -1e30f, l = 0.f, o = 0.f;
  const int nch = ((q0 + 3) >> 6) + 1;
  for (int ch = 0; ch < nch; ++ch) {
    const int k0 = ch << 6;
    __syncthreads();
#pragma unroll
    for (int it = 0; it < 4; ++it) {
      const int idx = it * 1024 + tid * 4;
      const int rr = idx >> 6, d0 = idx & 63;
      const size_t g = (size_t)(k0 + rr) * 3072 + d0;
      *(float4*)&Ks[rr * 68 + d0] = *(const float4*)&kb[g];
      const float4 vv = *(const float4*)&vb[g];
      Vt[(d0 + 0) * 68 + rr] = vv.x;
      Vt[(d0 + 1) * 68 + rr] = vv.y;
      Vt[(d0 + 2) * 68 + rr] = vv.z;
      Vt[(d0 + 3) * 68 + rr] = vv.w;
    }
    __syncthreads();
    if (k0 <= qi) {
      float sacc = 0.f;
      const float* kr = &Ks[lane * 68];
#pragma unroll
      for (int db = 0; db < 16; ++db) {
        const float4 kv = *(const float4*)(kr + db * 4);
        const float4 qv = *(const float4*)&qs[w][db * 4];
        sacc += kv.x * qv.x + kv.y * qv.y + kv.z * qv.z + kv.w * qv.w;
      }
      const float s = (k0 + lane <= qi) ? sacc : -1e30f;
      float mt = s;
#pragma unroll
      for (int off = 32; off > 0; off >>= 1) mt = fmaxf(mt, __shfl_xor(mt, off));
      const float mnew = fmaxf(m, mt);
      const float p = expf(s - mnew);
      const float alpha = expf(m - mnew);
      float ssum = p;
#pragma unroll
      for (int off = 32; off > 0; off >>= 1) ssum += __shfl_xor(ssum, off);
      l = l * alpha + ssum;
      o *= alpha;
      m = mnew;
      ps[w][lane] = p;
      const float* vr = &Vt[lane * 68];
#pragma unroll
      for (int k2 = 0; k2 < 16; ++k2) {
        const float4 vv = *(const float4*)(vr + k2 * 4);
        const float4 pv = *(const float4*)&ps[w][k2 * 4];
        o += vv.x * pv.x + vv.y * pv.y + vv.z * pv.z + vv.w * pv.w;
      }
    }
  }
  obuf[((size_t)(b * Tc + qi)) * 1024 + h * 64 + lane] = o / l;
}

// ---------------------------------------------------------------- router (fp32) + top-2 append
__global__ __launch_bounds__(256) void router_kernel(const float* __restrict__ x2,
                                                     const float* __restrict__ rw,
                                                     int* __restrict__ cnt,
                                                     int* __restrict__ tok,
                                                     float* __restrict__ wt) {
  __shared__ float xr[1024];
  __shared__ float part[8][32];
  __shared__ float lg[8];
  const int row = blockIdx.x, tid = threadIdx.x;
  reinterpret_cast<float4*>(xr)[tid] = reinterpret_cast<const float4*>(x2 + (size_t)row * Dc)[tid];
  __syncthreads();
  const int e = tid >> 5, j = tid & 31;
  float p = 0.f;
  for (int d = j; d < Dc; d += 32) p += xr[d] * rw[e * Dc + d];
  part[e][j] = p;
  __syncthreads();
  if (tid < 8) {
    float s = 0.f;
    for (int q = 0; q < 32; ++q) s += part[tid][q];
    lg[tid] = s;
  }
  __syncthreads();
  if (tid == 0) {
    // top-2 on raw logits (softmax+eps+clip is monotone; ties -> lower index)
    int i0 = 0;
    for (int q = 1; q < 8; ++q) if (lg[q] > lg[i0]) i0 = q;
    int i1 = (i0 == 0) ? 1 : 0;
    for (int q = 0; q < 8; ++q) if (q != i0 && lg[q] > lg[i1]) i1 = q;
    float mx = lg[0];
    for (int q = 1; q < 8; ++q) mx = fmaxf(mx, lg[q]);
    float ex[8], s = 0.f;
    for (int q = 0; q < 8; ++q) { ex[q] = expf(lg[q] - mx); s += ex[q]; }
    const float inv = 1.f / s;
    float p0v = fminf(fmaxf(ex[i0] * inv + 1e-9f, 1e-9f), 1.f - 1e-9f);
    float p1v = fminf(fmaxf(ex[i1] * inv + 1e-9f, 1e-9f), 1.f - 1e-9f);
    const float sw = 1.f / (p0v + p1v);
    int p0 = atomicAdd(&cnt[i0], 1);
    tok[i0 * Mtok + p0] = row; wt[i0 * Mtok + p0] = p0v * sw;
    int p1 = atomicAdd(&cnt[i1], 1);
    tok[i1 * Mtok + p1] = row; wt[i1 * Mtok + p1] = p1v * sw;
  }
}

// ---------------------------------------------------------------- expert GEMM1: gather -> gelu -> hid
__global__ __launch_bounds__(256) void gemm_e1_kernel(const u16* __restrict__ x2b,
                                                      const u16* __restrict__ w1,
                                                      const int* __restrict__ cnt,
                                                      const int* __restrict__ tok,
                                                      u16* __restrict__ hid) {
  const int bn = blockIdx.x;            // FF/128 = 32
  const int e = blockIdx.y >> 5, it = blockIdx.y & 31;
  const int n_e = cnt[e];
  if (it * 128 >= n_e) return;
  int offs = 0;
  for (int q = 0; q < 8; ++q) offs += (q < e) ? cnt[q] : 0;
  __shared__ u16 As[128 * 32], Bs[128 * 32];
  const int tid = threadIdx.x;
  const int r = tid >> 2, kk = (tid & 3) * 8;
  const int i0 = it * 128 + r, i1 = i0 + 64;
  const int t0 = tok[e * Mtok + ((i0 < n_e) ? i0 : (n_e - 1))];
  const int t1 = tok[e * Mtok + ((i1 < n_e) ? i1 : (n_e - 1))];
  const u16* a0 = x2b + (size_t)t0 * 1024 + kk;
  const u16* a1 = x2b + (size_t)t1 * 1024 + kk;
  const u16* b0 = w1 + (size_t)e * FFc * Dc + (size_t)(bn * 128 + r) * 1024 + kk;
  const u16* b1 = b0 + (size_t)64 * 1024;
  f32x4 acc[4][4] = {};
  gemm_mfma_core(a0, a1, b0, b1, 1024, As, Bs, acc);
  const int lane = tid & 63, wave = tid >> 6;
  const int wm = (wave & 1) * 64, wn = (wave >> 1) * 64;
  const int col = lane & 15, rb = (lane >> 4) * 4;
#pragma unroll
  for (int mt = 0; mt < 4; ++mt)
#pragma unroll
    for (int rr = 0; rr < 4; ++rr) {
      const int i = it * 128 + wm + mt * 16 + rb + rr;
      if (i < n_e) {
        const size_t hrow = (size_t)(offs + i) * FFc;
#pragma unroll
        for (int nt = 0; nt < 4; ++nt) {
          const int n = bn * 128 + wn + nt * 16 + col;
          hid[hrow + n] = f2bf(gelu_f(acc[mt][nt][rr]));
        }
      }
    }
}

// ---------------------------------------------------------------- expert GEMM2: hid x w2^T -> scatter-add
__global__ __launch_bounds__(256) void gemm_e2_kernel(const u16* __restrict__ hid,
                                                      const u16* __restrict__ w2,
                                                      const int* __restrict__ cnt,
                                                      const int* __restrict__ tok,
                                                      const float* __restrict__ wt,
                                                      float* __restrict__ out) {
  const int bn = blockIdx.x;            // D/128 = 8
  const int e = blockIdx.y >> 5, it = blockIdx.y & 31;
  const int n_e = cnt[e];
  if (it * 128 >= n_e) return;
  int offs = 0;
  for (int q = 0; q < 8; ++q) offs += (q < e) ? cnt[q] : 0;
  __shared__ u16 As[128 * 32], Bs[128 * 32];
  const int tid = threadIdx.x;
  const int r = tid >> 2, kk = (tid & 3) * 8;
  const int i0 = it * 128 + r, i1 = i0 + 64;
  const int ri0 = offs + ((i0 < n_e) ? i0 : (n_e - 1));
  const int ri1 = offs + ((i1 < n_e) ? i1 : (n_e - 1));
  const u16* a0 = hid + (size_t)ri0 * FFc + kk;
  const u16* a1 = hid + (size_t)ri1 * FFc + kk;
  const u16* b0 = w2 + (size_t)e * Dc * FFc + (size_t)(bn * 128 + r) * FFc + kk;
  const u16* b1 = b0 + (size_t)64 * FFc;
  f32x4 acc[4][4] = {};
  gemm_mfma_core(a0, a1, b0, b1, FFc, As, Bs, acc);
  const int lane = tid & 63, wave = tid >> 6;
  const int wm = (wave & 1) * 64, wn = (wave >> 1) * 64;
  const int col = lane & 15, rb = (lane >> 4) * 4;
#pragma unroll
  for (int mt = 0; mt < 4; ++mt)
#pragma unroll
    for (int rr = 0; rr < 4; ++rr) {
      const int i = it * 128 + wm + mt * 16 + rb + rr;
      if (i < n_e) {
        const int tk = tok[e * Mtok + i];
        const float wgt = wt[e * Mtok + i];
#pragma unroll
        for (int nt = 0; nt < 4; ++nt) {
          const int n = bn * 128 + wn + nt * 16 + col;
          atomicAdd(&out[(size_t)tk * 1024 + n], wgt * acc[mt][nt][rr]);
        }
      }
    }
}

// ---------------------------------------------------------------- workspace layout (bytes)
constexpr size_t OFF_WQKV3 = 0;                                       // 3 planes wqkv  18,874,368
constexpr size_t OFF_WPROJ3 = 18874368;                               // 3 planes wproj  6,291,456
constexpr size_t OFF_W1 = 25165824;                                   // w1 bf16        67,108,864
constexpr size_t OFF_W2 = 92274688;                                   // w2 bf16        67,108,864
constexpr size_t OFF_HPL = 159383552;                                 // h planes (then o planes) 25,165,824
constexpr size_t OFF_QKV = 184549376;                                 // qkv fp32 50,331,648 (then hid overlay)
constexpr size_t OFF_OF = 234881024;                                  // o fp32 (then xmid fp32) 16,777,216
constexpr size_t OFF_X2 = 251658240;                                  // x2 bf16 8,388,608
constexpr size_t OFF_CNT = 260046848;
constexpr size_t OFF_TOK = OFF_CNT + 256;
constexpr size_t OFF_WTL = OFF_TOK + (size_t)Ec * Mtok * 4;
// hid (bf16, 2*Mtok*FF = 67,108,864 B) overlays [OFF_QKV, OFF_X2): both dead by then.

extern "C" void kernel_launch(void* const* d_in, const int* in_sizes, int n_in,
                              void* d_out, int out_size, void* d_ws, size_t ws_size,
                              hipStream_t stream) {
  const float* x = (const float*)d_in[0];
  const float* c = (const float*)d_in[1];
  const float* ln1_w = (const float*)d_in[2];
  const float* w_qkv = (const float*)d_in[3];
  const float* w_proj = (const float*)d_in[4];
  const float* ln2_w = (const float*)d_in[5];
  const float* router_w = (const float*)d_in[6];
  const float* ew1 = (const float*)d_in[7];
  const float* ew2 = (const float*)d_in[8];
  float* out = (float*)d_out;
  char* ws = (char*)d_ws;

  u16* wqkv3 = (u16*)(ws + OFF_WQKV3);
  u16* wproj3 = (u16*)(ws + OFF_WPROJ3);
  u16* w1_bf = (u16*)(ws + OFF_W1);
  u16* w2_bf = (u16*)(ws + OFF_W2);
  u16* hpl = (u16*)(ws + OFF_HPL);       // h planes, later o planes
  float* qkvf = (float*)(ws + OFF_QKV);
  float* of = (float*)(ws + OFF_OF);     // o fp32, later xmid fp32
  u16* x2_bf = (u16*)(ws + OFF_X2);
  u16* hid_bf = (u16*)(ws + OFF_QKV);    // overlay (qkv+of dead by expert phase)
  int* cnt = (int*)(ws + OFF_CNT);
  int* tok = (int*)(ws + OFF_TOK);
  float* wtl = (float*)(ws + OFF_WTL);

  // 1) weight conversions (inputs restored every call)
  split3_kernel<<<(3 * Dc * Dc / 4 + 255) / 256, 256, 0, stream>>>(w_qkv, wqkv3, PS_WQKV, 3 * Dc * Dc / 4);
  split3_kernel<<<(Dc * Dc / 4 + 255) / 256, 256, 0, stream>>>(w_proj, wproj3, PS_WPROJ, Dc * Dc / 4);
  {
    int n4 = Ec * FFc * Dc / 4;
    cvt_bf16_kernel<<<(n4 + 255) / 256, 256, 0, stream>>>(ew1, w1_bf, n4);
    cvt_bf16_kernel<<<(n4 + 255) / 256, 256, 0, stream>>>(ew2, w2_bf, n4);
  }
  // 2) h = LN1(x)*w + c -> 3 bf16 planes
  ln1_kernel<<<Mtok, 256, 0, stream>>>(x, ln1_w, c, hpl);
  // 3) qkv = h @ w_qkv^T  (split-3, fp32 out)
  gemm_qkv_kernel<<<dim3(24, 32), 256, 0, stream>>>(hpl, wqkv3, qkvf);
  // 4) causal attention, fp32
  attn_f32_kernel<<<dim3(Tc / 4, Bc * Hc), 256, 0, stream>>>(qkvf, of);
  // 5) split o -> planes (h planes dead)
  split3_kernel<<<(Mtok * Dc / 4 + 255) / 256, 256, 0, stream>>>(of, hpl, PS_H, Mtok * Dc / 4);
  // 6) xmid = x + o @ w_proj^T  (split-3, fp32 out; overwrites o fp32)
  gemm_proj_kernel<<<dim3(8, 32), 256, 0, stream>>>(hpl, wproj3, x, of);
  // 7) x2 = LN2(xmid): fp32 -> d_out (MoE accumulates on top), bf16 -> x2_bf
  ln2_kernel<<<Mtok, 256, 0, stream>>>(of, ln2_w, out, x2_bf);
  // 8) router -> per-expert token lists
  (void)hipMemsetAsync(cnt, 0, Ec * sizeof(int), stream);
  router_kernel<<<Mtok, 256, 0, stream>>>(out, router_w, cnt, tok, wtl);
  // 9) experts (sparse top-2, bf16 MFMA)
  gemm_e1_kernel<<<dim3(32, 256), 256, 0, stream>>>(x2_bf, w1_bf, cnt, tok, hid_bf);
  gemm_e2_kernel<<<dim3(8, 256), 256, 0, stream>>>(hid_bf, w2_bf, cnt, tok, wtl, out);
}

// Round 3
// 1479.202 us; speedup vs baseline: 1.1384x; 1.1384x over previous
//
#include <hip/hip_runtime.h>
#include <cstdint>
#include <cstddef>

// ---------------------------------------------------------------------------
// NoiseBlockMoE (B=4,T=1024,D=1024,H=16,E=8,top2,FF=4096)
// Round 3: attention restructured — 16 q-rows/block, no V transpose,
// conflict-free LDS patterns, K cached in regs. Rest unchanged from round 2.
// ---------------------------------------------------------------------------

#define AS1 __attribute__((address_space(1)))
#define AS3 __attribute__((address_space(3)))

typedef unsigned short u16;
typedef __attribute__((ext_vector_type(8))) short short8;   // 8 bf16 = 4 VGPR
typedef __attribute__((ext_vector_type(4))) float f32x4;

constexpr int Bc = 4, Tc = 1024, Dc = 1024, Hc = 16, Ec = 8, FFc = 4096;
constexpr int Mtok = Bc * Tc;   // 4096 tokens

// plane strides (elements)
constexpr size_t PS_WQKV = (size_t)3 * Dc * Dc;   // 3145728
constexpr size_t PS_WPROJ = (size_t)Dc * Dc;      // 1048576
constexpr size_t PS_H = (size_t)Mtok * Dc;        // 4194304

__device__ __forceinline__ u16 f2bf(float f) {              // RNE f32->bf16
  unsigned u = __float_as_uint(f);
  u += 0x7fffu + ((u >> 16) & 1u);
  return (u16)(u >> 16);
}
__device__ __forceinline__ float bf2f(u16 v) { return __uint_as_float(((unsigned)v) << 16); }
__device__ __forceinline__ float gelu_f(float v) {          // exact GELU (erf)
  return 0.5f * v * (1.0f + erff(v * 0.70710678118654752440f));
}

// ---------------------------------------------------------------- cvt f32->bf16 (plain)
__global__ __launch_bounds__(256) void cvt_bf16_kernel(const float* __restrict__ in,
                                                       u16* __restrict__ out, int n4) {
  int i = blockIdx.x * 256 + threadIdx.x;
  if (i >= n4) return;
  float4 v = reinterpret_cast<const float4*>(in)[i];
  uint2 o;
  o.x = (unsigned)f2bf(v.x) | ((unsigned)f2bf(v.y) << 16);
  o.y = (unsigned)f2bf(v.z) | ((unsigned)f2bf(v.w) << 16);
  reinterpret_cast<uint2*>(out)[i] = o;
}

// ---------------------------------------------------------------- fp32 -> 3 bf16 planes
__global__ __launch_bounds__(256) void split3_kernel(const float* __restrict__ in,
                                                     u16* __restrict__ out,
                                                     size_t ps, int n4) {
  int i = blockIdx.x * 256 + threadIdx.x;
  if (i >= n4) return;
  float4 v = reinterpret_cast<const float4*>(in)[i];
  float a[4] = {v.x, v.y, v.z, v.w};
  unsigned h[4], md[4], lo[4];
#pragma unroll
  for (int j = 0; j < 4; ++j) {
    u16 hh = f2bf(a[j]); float r = a[j] - bf2f(hh);
    u16 mm = f2bf(r);    float r2 = r - bf2f(mm);
    u16 ll = f2bf(r2);
    h[j] = hh; md[j] = mm; lo[j] = ll;
  }
  uint2 o0, o1, o2;
  o0.x = h[0] | (h[1] << 16);  o0.y = h[2] | (h[3] << 16);
  o1.x = md[0] | (md[1] << 16); o1.y = md[2] | (md[3] << 16);
  o2.x = lo[0] | (lo[1] << 16); o2.y = lo[2] | (lo[3] << 16);
  const size_t base = (size_t)i * 4;
  *(uint2*)&out[base] = o0;
  *(uint2*)&out[ps + base] = o1;
  *(uint2*)&out[2 * ps + base] = o2;
}

// ---------------------------------------------------------------- LN1 (+c) -> 3 bf16 planes
__global__ __launch_bounds__(256) void ln1_kernel(const float* __restrict__ x,
                                                  const float* __restrict__ w,
                                                  const float* __restrict__ c,
                                                  u16* __restrict__ hp) {
  const int row = blockIdx.x, tid = threadIdx.x;
  const int b = row >> 10;   // T=1024
  const float4 v = reinterpret_cast<const float4*>(x + (size_t)row * Dc)[tid];
  __shared__ float red[256];
  red[tid] = v.x + v.y + v.z + v.w;
  __syncthreads();
  for (int s = 128; s > 0; s >>= 1) { if (tid < s) red[tid] += red[tid + s]; __syncthreads(); }
  const float mu = red[0] * (1.0f / Dc);
  __syncthreads();
  const float dx = v.x - mu, dy = v.y - mu, dz = v.z - mu, dw = v.w - mu;
  red[tid] = dx * dx + dy * dy + dz * dz + dw * dw;
  __syncthreads();
  for (int s = 128; s > 0; s >>= 1) { if (tid < s) red[tid] += red[tid + s]; __syncthreads(); }
  const float rs = rsqrtf(red[0] * (1.0f / Dc) + 1e-5f);
  const float4 wv = reinterpret_cast<const float4*>(w)[tid];
  const float4 cv = reinterpret_cast<const float4*>(c + (size_t)b * Dc)[tid];
  float a[4];
  a[0] = dx * rs * wv.x + cv.x; a[1] = dy * rs * wv.y + cv.y;
  a[2] = dz * rs * wv.z + cv.z; a[3] = dw * rs * wv.w + cv.w;
  unsigned h[4], md[4], lo[4];
#pragma unroll
  for (int j = 0; j < 4; ++j) {
    u16 hh = f2bf(a[j]); float r = a[j] - bf2f(hh);
    u16 mm = f2bf(r);    float r2 = r - bf2f(mm);
    u16 ll = f2bf(r2);
    h[j] = hh; md[j] = mm; lo[j] = ll;
  }
  uint2 o0, o1, o2;
  o0.x = h[0] | (h[1] << 16);  o0.y = h[2] | (h[3] << 16);
  o1.x = md[0] | (md[1] << 16); o1.y = md[2] | (md[3] << 16);
  o2.x = lo[0] | (lo[1] << 16); o2.y = lo[2] | (lo[3] << 16);
  const size_t base = (size_t)row * Dc + tid * 4;
  *(uint2*)&hp[base] = o0;
  *(uint2*)&hp[PS_H + base] = o1;
  *(uint2*)&hp[2 * PS_H + base] = o2;
}

// ---------------------------------------------------------------- LN2 -> f32 (d_out) + bf16
__global__ __launch_bounds__(256) void ln2_kernel(const float* __restrict__ xin,
                                                  const float* __restrict__ w,
                                                  float* __restrict__ xf,
                                                  u16* __restrict__ xb) {
  const int row = blockIdx.x, tid = threadIdx.x;
  const float4 v = reinterpret_cast<const float4*>(xin + (size_t)row * Dc)[tid];
  __shared__ float red[256];
  red[tid] = v.x + v.y + v.z + v.w;
  __syncthreads();
  for (int s = 128; s > 0; s >>= 1) { if (tid < s) red[tid] += red[tid + s]; __syncthreads(); }
  const float mu = red[0] * (1.0f / Dc);
  __syncthreads();
  const float dx = v.x - mu, dy = v.y - mu, dz = v.z - mu, dw = v.w - mu;
  red[tid] = dx * dx + dy * dy + dz * dz + dw * dw;
  __syncthreads();
  for (int s = 128; s > 0; s >>= 1) { if (tid < s) red[tid] += red[tid + s]; __syncthreads(); }
  const float rs = rsqrtf(red[0] * (1.0f / Dc) + 1e-5f);
  const float4 wv = reinterpret_cast<const float4*>(w)[tid];
  float4 ov;
  ov.x = dx * rs * wv.x; ov.y = dy * rs * wv.y; ov.z = dz * rs * wv.z; ov.w = dw * rs * wv.w;
  reinterpret_cast<float4*>(xf + (size_t)row * Dc)[tid] = ov;
  uint2 o;
  o.x = (unsigned)f2bf(ov.x) | ((unsigned)f2bf(ov.y) << 16);
  o.y = (unsigned)f2bf(ov.z) | ((unsigned)f2bf(ov.w) << 16);
  reinterpret_cast<uint2*>(xb + (size_t)row * Dc)[tid] = o;
}

// ---------------------------------------------------------------- MFMA GEMM core (single, bf16)
__device__ __forceinline__ void gemm_mfma_core(const u16* a0, const u16* a1,
                                               const u16* b0, const u16* b1,
                                               int K, u16* As, u16* Bs, f32x4 acc[4][4]) {
  const int tid = threadIdx.x;
  const int lane = tid & 63;
  const int wave = tid >> 6;
  const int wm = (wave & 1) * 64;
  const int wn = (wave >> 1) * 64;
  const int frow = lane & 15;
  const int fk = (lane >> 4) * 8;
  int aoff[4], boff[4];
#pragma unroll
  for (int t = 0; t < 4; ++t) {
    aoff[t] = (wm + t * 16 + frow) * 32 + fk;
    boff[t] = (wn + t * 16 + frow) * 32 + fk;
  }
  const int lds0 = tid * 8;
  for (int k0 = 0; k0 < K; k0 += 32) {
    __builtin_amdgcn_global_load_lds((AS1 void*)a0, (AS3 void*)(As + lds0), 16, 0, 0);
    __builtin_amdgcn_global_load_lds((AS1 void*)a1, (AS3 void*)(As + 2048 + lds0), 16, 0, 0);
    __builtin_amdgcn_global_load_lds((AS1 void*)b0, (AS3 void*)(Bs + lds0), 16, 0, 0);
    __builtin_amdgcn_global_load_lds((AS1 void*)b1, (AS3 void*)(Bs + 2048 + lds0), 16, 0, 0);
    a0 += 32; a1 += 32; b0 += 32; b1 += 32;
    __syncthreads();
    short8 af[4], bfr[4];
#pragma unroll
    for (int t = 0; t < 4; ++t) af[t] = *(const short8*)(As + aoff[t]);
#pragma unroll
    for (int t = 0; t < 4; ++t) bfr[t] = *(const short8*)(Bs + boff[t]);
#pragma unroll
    for (int mt = 0; mt < 4; ++mt)
#pragma unroll
      for (int nt = 0; nt < 4; ++nt)
        acc[mt][nt] = __builtin_amdgcn_mfma_f32_16x16x32_bf16(af[mt], bfr[nt], acc[mt][nt], 0, 0, 0);
    __syncthreads();
  }
}

// ---------------------------------------------------------------- split-3 GEMM core: 6 plane-pair sweeps
__device__ __forceinline__ void gemm_split_core(const u16* A0, const u16* A1, size_t Aps,
                                                const u16* B0, const u16* B1, size_t Bps,
                                                int K, u16* As, u16* Bs, f32x4 acc[4][4]) {
  const int PA[6] = {0, 0, 1, 1, 0, 2};
  const int PB[6] = {0, 1, 0, 1, 2, 0};
  for (int t6 = 0; t6 < 6; ++t6) {
    gemm_mfma_core(A0 + PA[t6] * Aps, A1 + PA[t6] * Aps,
                   B0 + PB[t6] * Bps, B1 + PB[t6] * Bps, K, As, Bs, acc);
  }
}

// ---------------------------------------------------------------- qkv split GEMM -> fp32
__global__ __launch_bounds__(256) void gemm_qkv_kernel(const u16* __restrict__ A,
                                                       const u16* __restrict__ Bw,
                                                       float* __restrict__ Cout) {
  __shared__ u16 As[128 * 32], Bs[128 * 32];
  const int bn = blockIdx.x, bm = blockIdx.y, tid = threadIdx.x;
  const int r = tid >> 2, kk = (tid & 3) * 8;
  const u16* a0 = A + (size_t)(bm * 128 + r) * 1024 + kk;
  const u16* a1 = a0 + (size_t)64 * 1024;
  const u16* b0 = Bw + (size_t)(bn * 128 + r) * 1024 + kk;
  const u16* b1 = b0 + (size_t)64 * 1024;
  f32x4 acc[4][4] = {};
  gemm_split_core(a0, a1, PS_H, b0, b1, PS_WQKV, 1024, As, Bs, acc);
  const int lane = tid & 63, wave = tid >> 6;
  const int wm = (wave & 1) * 64, wn = (wave >> 1) * 64;
  const int col = lane & 15, rb = (lane >> 4) * 4;
#pragma unroll
  for (int mt = 0; mt < 4; ++mt)
#pragma unroll
    for (int rr = 0; rr < 4; ++rr) {
      const int m = bm * 128 + wm + mt * 16 + rb + rr;
#pragma unroll
      for (int nt = 0; nt < 4; ++nt) {
        const int n = bn * 128 + wn + nt * 16 + col;
        Cout[(size_t)m * 3072 + n] = acc[mt][nt][rr];
      }
    }
}

// ---------------------------------------------------------------- proj split GEMM + residual -> fp32
__global__ __launch_bounds__(256) void gemm_proj_kernel(const u16* __restrict__ A,
                                                        const u16* __restrict__ Bw,
                                                        const float* __restrict__ xres,
                                                        float* __restrict__ xmid) {
  __shared__ u16 As[128 * 32], Bs[128 * 32];
  const int bn = blockIdx.x, bm = blockIdx.y, tid = threadIdx.x;
  const int r = tid >> 2, kk = (tid & 3) * 8;
  const u16* a0 = A + (size_t)(bm * 128 + r) * 1024 + kk;
  const u16* a1 = a0 + (size_t)64 * 1024;
  const u16* b0 = Bw + (size_t)(bn * 128 + r) * 1024 + kk;
  const u16* b1 = b0 + (size_t)64 * 1024;
  f32x4 acc[4][4] = {};
  gemm_split_core(a0, a1, PS_H, b0, b1, PS_WPROJ, 1024, As, Bs, acc);
  const int lane = tid & 63, wave = tid >> 6;
  const int wm = (wave & 1) * 64, wn = (wave >> 1) * 64;
  const int col = lane & 15, rb = (lane >> 4) * 4;
#pragma unroll
  for (int mt = 0; mt < 4; ++mt)
#pragma unroll
    for (int rr = 0; rr < 4; ++rr) {
      const int m = bm * 128 + wm + mt * 16 + rb + rr;
#pragma unroll
      for (int nt = 0; nt < 4; ++nt) {
        const int n = bn * 128 + wn + nt * 16 + col;
        xmid[(size_t)m * 1024 + n] = xres[(size_t)m * 1024 + n] + acc[mt][nt][rr];
      }
    }
}

// ---------------------------------------------------------------- attention, fp32 flash (scalar, v2)
// Block = 4 waves, 16 q rows of one (b,h): wave w -> rows q0+4w..q0+4w+3.
// K,V row-major in LDS (stride 68). Per chunk: wave caches its K row (lane=k)
// in 64 VGPRs, batches 4 rows' scores, then one PV sweep (V column reads are
// bank-spread: (4k+lane)%32 covers all banks; ps reads are broadcasts).
__global__ __launch_bounds__(256) void attn_f32_kernel(const float* __restrict__ qkv,
                                                       float* __restrict__ obuf) {
  const int tid = threadIdx.x, lane = tid & 63, w = tid >> 6;
  const int bh = blockIdx.y, b = bh >> 4, h = bh & 15;
  const int q0 = blockIdx.x * 16;
  const int r0 = q0 + w * 4;
  __shared__ float Ks[64 * 68];
  __shared__ float Vs[64 * 68];
  __shared__ float qs[16][64];
  __shared__ float ps[4][4][64];
  {
    const int r = tid >> 4, dg = (tid & 15) * 4;
    const float4 qv = *(const float4*)&qkv[((size_t)(b * Tc + q0 + r)) * 3072 + h * 64 + dg];
    qs[r][dg + 0] = qv.x * 0.125f;   // 1/sqrt(64), exact
    qs[r][dg + 1] = qv.y * 0.125f;
    qs[r][dg + 2] = qv.z * 0.125f;
    qs[r][dg + 3] = qv.w * 0.125f;
  }
  const float* kb = qkv + (size_t)b * Tc * 3072 + 1024 + h * 64;
  const float* vb = kb + 1024;
  float m[4] = {-1e30f, -1e30f, -1e30f, -1e30f};
  float l[4] = {0.f, 0.f, 0.f, 0.f};
  float o[4] = {0.f, 0.f, 0.f, 0.f};
  const int nch = ((q0 + 15) >> 6) + 1;
  for (int ch = 0; ch < nch; ++ch) {
    const int k0 = ch << 6;
    __syncthreads();
#pragma unroll
    for (int it = 0; it < 4; ++it) {
      const int rr = it * 16 + (tid >> 4), dg = (tid & 15) * 4;
      const size_t g = (size_t)(k0 + rr) * 3072 + dg;
      *(float4*)&Ks[rr * 68 + dg] = *(const float4*)&kb[g];
      *(float4*)&Vs[rr * 68 + dg] = *(const float4*)&vb[g];
    }
    __syncthreads();
    if (k0 <= r0 + 3) {                  // wave-uniform causal skip
      float kr[64];                      // this lane's K row (lane = k index)
#pragma unroll
      for (int dg = 0; dg < 16; ++dg)
        *(float4*)&kr[dg * 4] = *(const float4*)&Ks[lane * 68 + dg * 4];
#pragma unroll
      for (int j = 0; j < 4; ++j) {
        const int qi = r0 + j;
        float s = 0.f;
#pragma unroll
        for (int dg = 0; dg < 16; ++dg) {
          const float4 qv = *(const float4*)&qs[w * 4 + j][dg * 4];   // broadcast
          s += kr[dg * 4 + 0] * qv.x + kr[dg * 4 + 1] * qv.y
             + kr[dg * 4 + 2] * qv.z + kr[dg * 4 + 3] * qv.w;
        }
        if (k0 + lane > qi) s = -1e30f;
        float mt = s;
#pragma unroll
        for (int off = 32; off > 0; off >>= 1) mt = fmaxf(mt, __shfl_xor(mt, off));
        const float mnew = fmaxf(m[j], mt);
        const float p = __expf(s - mnew);
        const float alpha = __expf(m[j] - mnew);
        float ss = p;
#pragma unroll
        for (int off = 32; off > 0; off >>= 1) ss += __shfl_xor(ss, off);
        m[j] = mnew;
        l[j] = l[j] * alpha + ss;
        o[j] *= alpha;
        ps[w][j][lane] = p;              // bank = lane%32: 2-way, free
      }
      __builtin_amdgcn_wave_barrier();   // order ps writes before cross-lane reads (same wave)
#pragma unroll
      for (int kg = 0; kg < 16; ++kg) {
        const float v0 = Vs[(kg * 4 + 0) * 68 + lane];   // (4k+lane)%32: all banks, free
        const float v1 = Vs[(kg * 4 + 1) * 68 + lane];
        const float v2 = Vs[(kg * 4 + 2) * 68 + lane];
        const float v3 = Vs[(kg * 4 + 3) * 68 + lane];
#pragma unroll
        for (int j = 0; j < 4; ++j) {
          const float4 pv = *(const float4*)&ps[w][j][kg * 4];        // broadcast
          o[j] += pv.x * v0 + pv.y * v1 + pv.z * v2 + pv.w * v3;
        }
      }
    }
  }
#pragma unroll
  for (int j = 0; j < 4; ++j)
    obuf[((size_t)(b * Tc + r0 + j)) * 1024 + h * 64 + lane] = o[j] / l[j];
}

// ---------------------------------------------------------------- router (fp32) + top-2 append
__global__ __launch_bounds__(256) void router_kernel(const float* __restrict__ x2,
                                                     const float* __restrict__ rw,
                                                     int* __restrict__ cnt,
                                                     int* __restrict__ tok,
                                                     float* __restrict__ wt) {
  __shared__ float xr[1024];
  __shared__ float part[8][32];
  __shared__ float lg[8];
  const int row = blockIdx.x, tid = threadIdx.x;
  reinterpret_cast<float4*>(xr)[tid] = reinterpret_cast<const float4*>(x2 + (size_t)row * Dc)[tid];
  __syncthreads();
  const int e = tid >> 5, j = tid & 31;
  float p = 0.f;
  for (int d = j; d < Dc; d += 32) p += xr[d] * rw[e * Dc + d];
  part[e][j] = p;
  __syncthreads();
  if (tid < 8) {
    float s = 0.f;
    for (int q = 0; q < 32; ++q) s += part[tid][q];
    lg[tid] = s;
  }
  __syncthreads();
  if (tid == 0) {
    int i0 = 0;
    for (int q = 1; q < 8; ++q) if (lg[q] > lg[i0]) i0 = q;
    int i1 = (i0 == 0) ? 1 : 0;
    for (int q = 0; q < 8; ++q) if (q != i0 && lg[q] > lg[i1]) i1 = q;
    float mx = lg[0];
    for (int q = 1; q < 8; ++q) mx = fmaxf(mx, lg[q]);
    float ex[8], s = 0.f;
    for (int q = 0; q < 8; ++q) { ex[q] = expf(lg[q] - mx); s += ex[q]; }
    const float inv = 1.f / s;
    float p0v = fminf(fmaxf(ex[i0] * inv + 1e-9f, 1e-9f), 1.f - 1e-9f);
    float p1v = fminf(fmaxf(ex[i1] * inv + 1e-9f, 1e-9f), 1.f - 1e-9f);
    const float sw = 1.f / (p0v + p1v);
    int p0 = atomicAdd(&cnt[i0], 1);
    tok[i0 * Mtok + p0] = row; wt[i0 * Mtok + p0] = p0v * sw;
    int p1 = atomicAdd(&cnt[i1], 1);
    tok[i1 * Mtok + p1] = row; wt[i1 * Mtok + p1] = p1v * sw;
  }
}

// ---------------------------------------------------------------- expert GEMM1: gather -> gelu -> hid
__global__ __launch_bounds__(256) void gemm_e1_kernel(const u16* __restrict__ x2b,
                                                      const u16* __restrict__ w1,
                                                      const int* __restrict__ cnt,
                                                      const int* __restrict__ tok,
                                                      u16* __restrict__ hid) {
  const int bn = blockIdx.x;            // FF/128 = 32
  const int e = blockIdx.y >> 5, it = blockIdx.y & 31;
  const int n_e = cnt[e];
  if (it * 128 >= n_e) return;
  int offs = 0;
  for (int q = 0; q < 8; ++q) offs += (q < e) ? cnt[q] : 0;
  __shared__ u16 As[128 * 32], Bs[128 * 32];
  const int tid = threadIdx.x;
  const int r = tid >> 2, kk = (tid & 3) * 8;
  const int i0 = it * 128 + r, i1 = i0 + 64;
  const int t0 = tok[e * Mtok + ((i0 < n_e) ? i0 : (n_e - 1))];
  const int t1 = tok[e * Mtok + ((i1 < n_e) ? i1 : (n_e - 1))];
  const u16* a0 = x2b + (size_t)t0 * 1024 + kk;
  const u16* a1 = x2b + (size_t)t1 * 1024 + kk;
  const u16* b0 = w1 + (size_t)e * FFc * Dc + (size_t)(bn * 128 + r) * 1024 + kk;
  const u16* b1 = b0 + (size_t)64 * 1024;
  f32x4 acc[4][4] = {};
  gemm_mfma_core(a0, a1, b0, b1, 1024, As, Bs, acc);
  const int lane = tid & 63, wave = tid >> 6;
  const int wm = (wave & 1) * 64, wn = (wave >> 1) * 64;
  const int col = lane & 15, rb = (lane >> 4) * 4;
#pragma unroll
  for (int mt = 0; mt < 4; ++mt)
#pragma unroll
    for (int rr = 0; rr < 4; ++rr) {
      const int i = it * 128 + wm + mt * 16 + rb + rr;
      if (i < n_e) {
        const size_t hrow = (size_t)(offs + i) * FFc;
#pragma unroll
        for (int nt = 0; nt < 4; ++nt) {
          const int n = bn * 128 + wn + nt * 16 + col;
          hid[hrow + n] = f2bf(gelu_f(acc[mt][nt][rr]));
        }
      }
    }
}

// ---------------------------------------------------------------- expert GEMM2: hid x w2^T -> scatter-add
__global__ __launch_bounds__(256) void gemm_e2_kernel(const u16* __restrict__ hid,
                                                      const u16* __restrict__ w2,
                                                      const int* __restrict__ cnt,
                                                      const int* __restrict__ tok,
                                                      const float* __restrict__ wt,
                                                      float* __restrict__ out) {
  const int bn = blockIdx.x;            // D/128 = 8
  const int e = blockIdx.y >> 5, it = blockIdx.y & 31;
  const int n_e = cnt[e];
  if (it * 128 >= n_e) return;
  int offs = 0;
  for (int q = 0; q < 8; ++q) offs += (q < e) ? cnt[q] : 0;
  __shared__ u16 As[128 * 32], Bs[128 * 32];
  const int tid = threadIdx.x;
  const int r = tid >> 2, kk = (tid & 3) * 8;
  const int i0 = it * 128 + r, i1 = i0 + 64;
  const int ri0 = offs + ((i0 < n_e) ? i0 : (n_e - 1));
  const int ri1 = offs + ((i1 < n_e) ? i1 : (n_e - 1));
  const u16* a0 = hid + (size_t)ri0 * FFc + kk;
  const u16* a1 = hid + (size_t)ri1 * FFc + kk;
  const u16* b0 = w2 + (size_t)e * Dc * FFc + (size_t)(bn * 128 + r) * FFc + kk;
  const u16* b1 = b0 + (size_t)64 * FFc;
  f32x4 acc[4][4] = {};
  gemm_mfma_core(a0, a1, b0, b1, FFc, As, Bs, acc);
  const int lane = tid & 63, wave = tid >> 6;
  const int wm = (wave & 1) * 64, wn = (wave >> 1) * 64;
  const int col = lane & 15, rb = (lane >> 4) * 4;
#pragma unroll
  for (int mt = 0; mt < 4; ++mt)
#pragma unroll
    for (int rr = 0; rr < 4; ++rr) {
      const int i = it * 128 + wm + mt * 16 + rb + rr;
      if (i < n_e) {
        const int tk = tok[e * Mtok + i];
        const float wgt = wt[e * Mtok + i];
#pragma unroll
        for (int nt = 0; nt < 4; ++nt) {
          const int n = bn * 128 + wn + nt * 16 + col;
          atomicAdd(&out[(size_t)tk * 1024 + n], wgt * acc[mt][nt][rr]);
        }
      }
    }
}

// ---------------------------------------------------------------- workspace layout (bytes)
constexpr size_t OFF_WQKV3 = 0;                                       // 18,874,368
constexpr size_t OFF_WPROJ3 = 18874368;                               //  6,291,456
constexpr size_t OFF_W1 = 25165824;                                   // 67,108,864
constexpr size_t OFF_W2 = 92274688;                                   // 67,108,864
constexpr size_t OFF_HPL = 159383552;                                 // 25,165,824
constexpr size_t OFF_QKV = 184549376;                                 // 50,331,648 (later hid overlay)
constexpr size_t OFF_OF = 234881024;                                  // 16,777,216
constexpr size_t OFF_X2 = 251658240;                                  //  8,388,608
constexpr size_t OFF_CNT = 260046848;
constexpr size_t OFF_TOK = OFF_CNT + 256;
constexpr size_t OFF_WTL = OFF_TOK + (size_t)Ec * Mtok * 4;

extern "C" void kernel_launch(void* const* d_in, const int* in_sizes, int n_in,
                              void* d_out, int out_size, void* d_ws, size_t ws_size,
                              hipStream_t stream) {
  const float* x = (const float*)d_in[0];
  const float* c = (const float*)d_in[1];
  const float* ln1_w = (const float*)d_in[2];
  const float* w_qkv = (const float*)d_in[3];
  const float* w_proj = (const float*)d_in[4];
  const float* ln2_w = (const float*)d_in[5];
  const float* router_w = (const float*)d_in[6];
  const float* ew1 = (const float*)d_in[7];
  const float* ew2 = (const float*)d_in[8];
  float* out = (float*)d_out;
  char* ws = (char*)d_ws;

  u16* wqkv3 = (u16*)(ws + OFF_WQKV3);
  u16* wproj3 = (u16*)(ws + OFF_WPROJ3);
  u16* w1_bf = (u16*)(ws + OFF_W1);
  u16* w2_bf = (u16*)(ws + OFF_W2);
  u16* hpl = (u16*)(ws + OFF_HPL);       // h planes, later o planes
  float* qkvf = (float*)(ws + OFF_QKV);
  float* of = (float*)(ws + OFF_OF);     // o fp32, later xmid fp32
  u16* x2_bf = (u16*)(ws + OFF_X2);
  u16* hid_bf = (u16*)(ws + OFF_QKV);    // overlay (qkv+of dead by expert phase)
  int* cnt = (int*)(ws + OFF_CNT);
  int* tok = (int*)(ws + OFF_TOK);
  float* wtl = (float*)(ws + OFF_WTL);

  // 1) weight conversions (inputs restored every call)
  split3_kernel<<<(3 * Dc * Dc / 4 + 255) / 256, 256, 0, stream>>>(w_qkv, wqkv3, PS_WQKV, 3 * Dc * Dc / 4);
  split3_kernel<<<(Dc * Dc / 4 + 255) / 256, 256, 0, stream>>>(w_proj, wproj3, PS_WPROJ, Dc * Dc / 4);
  {
    int n4 = Ec * FFc * Dc / 4;
    cvt_bf16_kernel<<<(n4 + 255) / 256, 256, 0, stream>>>(ew1, w1_bf, n4);
    cvt_bf16_kernel<<<(n4 + 255) / 256, 256, 0, stream>>>(ew2, w2_bf, n4);
  }
  // 2) h = LN1(x)*w + c -> 3 bf16 planes
  ln1_kernel<<<Mtok, 256, 0, stream>>>(x, ln1_w, c, hpl);
  // 3) qkv = h @ w_qkv^T  (split-3, fp32 out)
  gemm_qkv_kernel<<<dim3(24, 32), 256, 0, stream>>>(hpl, wqkv3, qkvf);
  // 4) causal attention, fp32 (16 q rows per block)
  attn_f32_kernel<<<dim3(Tc / 16, Bc * Hc), 256, 0, stream>>>(qkvf, of);
  // 5) split o -> planes (h planes dead)
  split3_kernel<<<(Mtok * Dc / 4 + 255) / 256, 256, 0, stream>>>(of, hpl, PS_H, Mtok * Dc / 4);
  // 6) xmid = x + o @ w_proj^T  (split-3, fp32 out; overwrites o fp32)
  gemm_proj_kernel<<<dim3(8, 32), 256, 0, stream>>>(hpl, wproj3, x, of);
  // 7) x2 = LN2(xmid): fp32 -> d_out, bf16 -> x2_bf
  ln2_kernel<<<Mtok, 256, 0, stream>>>(of, ln2_w, out, x2_bf);
  // 8) router -> per-expert token lists
  (void)hipMemsetAsync(cnt, 0, Ec * sizeof(int), stream);
  router_kernel<<<Mtok, 256, 0, stream>>>(out, router_w, cnt, tok, wtl);
  // 9) experts (sparse top-2, bf16 MFMA)
  gemm_e1_kernel<<<dim3(32, 256), 256, 0, stream>>>(x2_bf, w1_bf, cnt, tok, hid_bf);
  gemm_e2_kernel<<<dim3(8, 256), 256, 0, stream>>>(hid_bf, w2_bf, cnt, tok, wtl, out);
}